// Round 3
// baseline (862.332 us; speedup 1.0000x reference)
//
#include <hip/hip_runtime.h>
#include <hip/hip_bf16.h>
#include <math.h>

#define WS_ALIGN(x) (((x) + 255) & ~(size_t)255)

// ---------------- zero-fill (replaces hipMemsetAsync for capture safety) ------------
__global__ void k_zero(unsigned* __restrict__ p, int count) {
    int i = blockIdx.x * 256 + threadIdx.x;
    if (i < count) p[i] = 0u;
}

// ---------------- degree histogram (out-deg for demb, in-deg for GCN norm) ----------
__global__ void k_hist(const int* __restrict__ ei, int E, int n,
                       unsigned* __restrict__ deg_out, unsigned* __restrict__ deg_in) {
    int e = blockIdx.x * 256 + threadIdx.x;
    if (e < E) {
        unsigned s = (unsigned)ei[e];
        unsigned d = (unsigned)ei[(size_t)E + e];
        if (s >= (unsigned)n) s = 0;   // armor: wrong-dtype garbage -> finite wrong answer, not fault
        if (d >= (unsigned)n) d = 0;
        atomicAdd(&deg_out[s], 1u);
        atomicAdd(&deg_in[d], 1u);
    }
}

// ---------------- max out-degree ----------------------------------------------------
__global__ void k_max(const unsigned* __restrict__ deg, int n, unsigned* __restrict__ out) {
    __shared__ unsigned red[4];
    int i = blockIdx.x * 256 + threadIdx.x;
    unsigned v = (i < n) ? deg[i] : 0u;
    for (int o = 32; o; o >>= 1) v = max(v, (unsigned)__shfl_down((int)v, o));
    if ((threadIdx.x & 63) == 0) red[threadIdx.x >> 6] = v;
    __syncthreads();
    if (threadIdx.x == 0) {
        unsigned m = max(max(red[0], red[1]), max(red[2], red[3]));
        atomicMax(out, m);
    }
}

// ---------------- 3-kernel exclusive scan of deg_in -> CSR row_start ----------------
__global__ void k_scan1(const unsigned* __restrict__ deg, int n,
                        unsigned* __restrict__ rs, unsigned* __restrict__ bs) {
    __shared__ unsigned tmp[256];
    int i = blockIdx.x * 256 + threadIdx.x;
    unsigned v = (i < n) ? deg[i] : 0u;
    tmp[threadIdx.x] = v;
    __syncthreads();
    for (int o = 1; o < 256; o <<= 1) {
        unsigned t = (threadIdx.x >= (unsigned)o) ? tmp[threadIdx.x - o] : 0u;
        __syncthreads();
        tmp[threadIdx.x] += t;
        __syncthreads();
    }
    if (i < n) rs[i] = tmp[threadIdx.x] - v;
    if (threadIdx.x == 255) bs[blockIdx.x] = tmp[255];
}

__global__ void k_scan2(unsigned* __restrict__ bs, int nb) {  // nb <= 512
    __shared__ unsigned tmp[512];
    unsigned v = ((int)threadIdx.x < nb) ? bs[threadIdx.x] : 0u;
    tmp[threadIdx.x] = v;
    __syncthreads();
    for (int o = 1; o < 512; o <<= 1) {
        unsigned t = (threadIdx.x >= (unsigned)o) ? tmp[threadIdx.x - o] : 0u;
        __syncthreads();
        tmp[threadIdx.x] += t;
        __syncthreads();
    }
    if ((int)threadIdx.x < nb) bs[threadIdx.x] = tmp[threadIdx.x] - v;
}

__global__ void k_scan3(unsigned* __restrict__ rs, const unsigned* __restrict__ bs,
                        unsigned* __restrict__ cur, int n) {
    int i = blockIdx.x * 256 + threadIdx.x;
    if (i < n) {
        unsigned v = rs[i] + bs[blockIdx.x];
        rs[i] = v;
        cur[i] = v;
    }
}

// ---------------- scatter edges into CSR (sorted by dst) ----------------------------
__global__ void k_scatter(const int* __restrict__ ei, int E, int n,
                          unsigned* __restrict__ cur, unsigned* __restrict__ csr,
                          int csr_cap) {
    int e = blockIdx.x * 256 + threadIdx.x;
    if (e < E) {
        unsigned s = (unsigned)ei[e];
        unsigned d = (unsigned)ei[(size_t)E + e];
        if (s >= (unsigned)n) s = 0;
        if (d >= (unsigned)n) d = 0;
        unsigned pos = atomicAdd(&cur[d], 1u);
        if (pos < (unsigned)csr_cap) csr[pos] = s;
    }
}

// ---------------- collapse deg_W/att_W to 2 scalars: dw = sigmoid(nd*A + B) ---------
__global__ void k_dot(const float* __restrict__ dW, const float* __restrict__ db,
                      const float* __restrict__ aW, const float* __restrict__ ab,
                      const unsigned* __restrict__ maxdeg, float* __restrict__ scal) {
    int t = threadIdx.x;  // 64 == H
    float a = dW[t] * aW[t];
    float b = db[t] * aW[t];
    for (int o = 32; o; o >>= 1) {
        a += __shfl_down(a, o);
        b += __shfl_down(b, o);
    }
    if (t == 0) {
        scal[0] = a;
        scal[1] = b + ab[0];
        scal[2] = (float)(*maxdeg);
    }
}

// ---------------- per-node scalars: scale1/2, nd, dinv ------------------------------
__global__ void k_nodeprep(const unsigned* __restrict__ deg_out,
                           const unsigned* __restrict__ deg_in,
                           const float* __restrict__ param1, const float* __restrict__ param2,
                           const float* __restrict__ scal, int n,
                           float* __restrict__ scale1, float* __restrict__ scale2,
                           float* __restrict__ ndarr, float* __restrict__ dinv) {
    int i = blockIdx.x * 256 + threadIdx.x;
    if (i >= n) return;
    float A = scal[0], B = scal[1], maxf = scal[2];
    float nd = (float)deg_out[i] / maxf;
    float s = fmaf(nd, A, B);
    float dw = 1.f / (1.f + expf(-s));
    scale1[i] = param1[i] * dw;
    scale2[i] = param2[i] * dw;
    ndarr[i] = nd;
    dinv[i] = rsqrtf((float)(deg_in[i] + 1u));  // self-loop included
}

// ---------------- dense GEMM: Hout[n,NOUT] = A[n,K] @ W[K,NOUT] ---------------------
// 64 rows/block, 256 threads; thread owns 2 cols x RPG rows. A staged transposed in LDS.
// VIRT=true generates A = [x*s1 | (nd*deg_W+deg_b)*s1] on the fly (GEMM1).
template <int K, int NOUT, int CPT, bool VIRT>
__global__ __launch_bounds__(256) void k_gemm(
    const float* __restrict__ A, const float* __restrict__ Wg, float* __restrict__ Hout,
    int n, const float* __restrict__ x, const float* __restrict__ ndarr,
    const float* __restrict__ scale1, const float* __restrict__ dW,
    const float* __restrict__ db) {
    constexpr int RPG = CPT / 4;       // rows per thread
    constexpr int AST = 68;            // LDS row stride (16B aligned, bank-skewed)
    constexpr bool FULL2 = (2 * CPT <= NOUT);
    __shared__ float Alds[K * AST];
    const int tid = threadIdx.x;
    const int blockRow = blockIdx.x * 64;

    for (int idx = tid; idx < 64 * K; idx += 256) {
        int row = idx / K, k = idx - row * K;
        int grow = blockRow + row;
        float v = 0.f;
        if (grow < n) {
            if (VIRT) {
                float s1 = scale1[grow];
                v = (k < 128) ? x[(size_t)grow * 128 + k] * s1
                              : fmaf(ndarr[grow], dW[k - 128], db[k - 128]) * s1;
            } else {
                v = A[(size_t)grow * K + k];
            }
        }
        Alds[k * AST + row] = v;
    }
    __syncthreads();

    const int c = tid % CPT;
    const int rg = tid / CPT;
    const int rbase = rg * RPG;
    float acc0[RPG], acc1[RPG];
#pragma unroll
    for (int r = 0; r < RPG; r++) { acc0[r] = 0.f; acc1[r] = 0.f; }

    for (int k = 0; k < K; k++) {
        float w0 = Wg[k * NOUT + c];
        float w1 = (FULL2 || c + CPT < NOUT) ? Wg[k * NOUT + c + CPT] : 0.f;
        const float* ar = &Alds[k * AST + rbase];
#pragma unroll
        for (int r = 0; r < RPG; r += 4) {
            float4 av = *(const float4*)(ar + r);
            acc0[r + 0] = fmaf(av.x, w0, acc0[r + 0]); acc1[r + 0] = fmaf(av.x, w1, acc1[r + 0]);
            acc0[r + 1] = fmaf(av.y, w0, acc0[r + 1]); acc1[r + 1] = fmaf(av.y, w1, acc1[r + 1]);
            acc0[r + 2] = fmaf(av.z, w0, acc0[r + 2]); acc1[r + 2] = fmaf(av.z, w1, acc1[r + 2]);
            acc0[r + 3] = fmaf(av.w, w0, acc0[r + 3]); acc1[r + 3] = fmaf(av.w, w1, acc1[r + 3]);
        }
    }
#pragma unroll
    for (int r = 0; r < RPG; r++) {
        int grow = blockRow + rbase + r;
        if (grow < n) {
            Hout[(size_t)grow * NOUT + c] = acc0[r];
            if (FULL2 || c + CPT < NOUT) Hout[(size_t)grow * NOUT + (c + CPT)] = acc1[r];
        }
    }
}

// ---------------- sparse aggregation (CSR gather, no atomics) + fused epilogue ------
// out[i] = dinv[i] * (sum_{j in N(i)} dinv[j]*h[j] + dinv[i]*h[i])
// EPI 1: relu(+b)*scale2 -> x1   EPI 2: relu(+b)+x1[:, :64] -> x2   EPI 3: +b, log_softmax
template <int D, int EPI>
__global__ void k_agg(const float* __restrict__ Hm, const unsigned* __restrict__ row_start,
                      const unsigned* __restrict__ deg_in, const unsigned* __restrict__ csr,
                      const float* __restrict__ dinv, const float* __restrict__ bias,
                      const float* __restrict__ aux, float* __restrict__ Out, int n) {
    int node = blockIdx.x;
    if (node >= n) return;
    int c = threadIdx.x;
    unsigned beg = row_start[node];
    unsigned cnt = deg_in[node];
    float di = dinv[node];
    bool act = (c < D);
    float acc = act ? di * Hm[(size_t)node * D + c] : 0.f;

    unsigned e = 0;
    for (; e + 1 < cnt; e += 2) {
        int s0 = (int)csr[beg + e];
        int s1 = (int)csr[beg + e + 1];
        float w0 = dinv[s0];
        float w1 = dinv[s1];
        if (act) {
            acc = fmaf(w0, Hm[(size_t)s0 * D + c], acc);
            acc = fmaf(w1, Hm[(size_t)s1 * D + c], acc);
        }
    }
    if (e < cnt) {
        int s0 = (int)csr[beg + e];
        float w0 = dinv[s0];
        if (act) acc = fmaf(w0, Hm[(size_t)s0 * D + c], acc);
    }
    acc *= di;

    if (EPI == 1) {
        float v = fmaxf(acc + bias[c], 0.f) * aux[node];
        Out[(size_t)node * D + c] = v;
    } else if (EPI == 2) {
        float v = fmaxf(acc + bias[c], 0.f) + aux[(size_t)node * 128 + c];
        Out[(size_t)node * D + c] = v;
    } else {
        float t = act ? (acc + bias[c]) : -INFINITY;
        float m = t;
        for (int o = 32; o; o >>= 1) m = fmaxf(m, __shfl_xor(m, o));
        float p = act ? expf(t - m) : 0.f;
        float ssum = p;
        for (int o = 32; o; o >>= 1) ssum += __shfl_xor(ssum, o);
        if (act) Out[(size_t)node * D + c] = t - m - logf(ssum);
    }
}

extern "C" void kernel_launch(void* const* d_in, const int* in_sizes, int n_in,
                              void* d_out, int out_size, void* d_ws, size_t ws_size,
                              hipStream_t stream) {
    const float* x = (const float*)d_in[0];
    const int* ei = (const int*)d_in[1];     // harness stages integers as int32
    const float* param1 = (const float*)d_in[2];
    const float* param2 = (const float*)d_in[3];
    const float* dW = (const float*)d_in[4];
    const float* db = (const float*)d_in[5];
    const float* aW = (const float*)d_in[6];
    const float* ab = (const float*)d_in[7];
    const float* W1 = (const float*)d_in[8];
    const float* b1 = (const float*)d_in[9];
    const float* W2 = (const float*)d_in[10];
    const float* b2 = (const float*)d_in[11];
    const float* W3 = (const float*)d_in[12];
    const float* b3 = (const float*)d_in[13];
    float* out = (float*)d_out;

    const int n = in_sizes[2];       // 100000 (param1 length)
    const int E = in_sizes[1] / 2;   // 1600000
    const int nb = (n + 255) / 256;  // 391 (must be <= 512 for k_scan2)

    char* p = (char*)d_ws;
    auto alloc = [&](size_t bytes) { char* r = p; p += WS_ALIGN(bytes); return r; };
    unsigned* deg_out = (unsigned*)alloc((size_t)n * 4);
    unsigned* deg_in = (unsigned*)alloc((size_t)n * 4);
    unsigned* maxdeg = (unsigned*)alloc(256);
    unsigned* row_start = (unsigned*)alloc((size_t)n * 4);
    unsigned* cursor = (unsigned*)alloc((size_t)n * 4);
    unsigned* bs = (unsigned*)alloc(4096);
    float* scal = (float*)alloc(256);
    float* scale1 = (float*)alloc((size_t)n * 4);
    float* scale2 = (float*)alloc((size_t)n * 4);
    float* ndarr = (float*)alloc((size_t)n * 4);
    float* dinv = (float*)alloc((size_t)n * 4);
    unsigned* csr = (unsigned*)alloc((size_t)E * 4);
    float* h1 = (float*)alloc((size_t)n * 128 * 4);  // h1; later h2 (lo half) + x2 (hi half)
    float* x1 = (float*)alloc((size_t)n * 128 * 4);  // x1; later h3
    float* h2 = h1;
    float* x2 = h1 + (size_t)n * 64;
    float* h3 = x1;

    dim3 b256(256);
    // zero deg_out, deg_in, AND maxdeg — span computed from actual (aligned) pointers
    int zcount = (int)((((char*)maxdeg - (char*)deg_out) + 256) / 4);
    k_zero<<<dim3((zcount + 255) / 256), b256, 0, stream>>>(deg_out, zcount);

    k_hist<<<dim3((E + 255) / 256), b256, 0, stream>>>(ei, E, n, deg_out, deg_in);
    k_max<<<dim3(nb), b256, 0, stream>>>(deg_out, n, maxdeg);
    k_scan1<<<dim3(nb), b256, 0, stream>>>(deg_in, n, row_start, bs);
    k_scan2<<<dim3(1), dim3(512), 0, stream>>>(bs, nb);
    k_scan3<<<dim3(nb), b256, 0, stream>>>(row_start, bs, cursor, n);
    k_scatter<<<dim3((E + 255) / 256), b256, 0, stream>>>(ei, E, n, cursor, csr, E);
    k_dot<<<dim3(1), dim3(64), 0, stream>>>(dW, db, aW, ab, maxdeg, scal);
    k_nodeprep<<<dim3(nb), b256, 0, stream>>>(deg_out, deg_in, param1, param2, scal, n,
                                              scale1, scale2, ndarr, dinv);

    int gb = (n + 63) / 64;
    k_gemm<192, 128, 64, true><<<dim3(gb), b256, 0, stream>>>(nullptr, W1, h1, n, x, ndarr,
                                                              scale1, dW, db);
    k_agg<128, 1><<<dim3(n), dim3(128), 0, stream>>>(h1, row_start, deg_in, csr, dinv, b1,
                                                     scale2, x1, n);
    k_gemm<128, 64, 32, false><<<dim3(gb), b256, 0, stream>>>(x1, W2, h2, n, nullptr, nullptr,
                                                              nullptr, nullptr, nullptr);
    k_agg<64, 2><<<dim3(n), dim3(64), 0, stream>>>(h2, row_start, deg_in, csr, dinv, b2, x1,
                                                   x2, n);
    k_gemm<64, 40, 32, false><<<dim3(gb), b256, 0, stream>>>(x2, W3, h3, n, nullptr, nullptr,
                                                             nullptr, nullptr, nullptr);
    k_agg<40, 3><<<dim3(n), dim3(64), 0, stream>>>(h3, row_start, deg_in, csr, dinv, b3,
                                                   nullptr, out, n);
}

// Round 10
// 816.308 us; speedup vs baseline: 1.0564x; 1.0564x over previous
//
#include <hip/hip_runtime.h>
#include <hip/hip_bf16.h>
#include <math.h>

#define WS_ALIGN(x) (((x) + 255) & ~(size_t)255)

// ---------------- zero-fill (replaces hipMemsetAsync for capture safety) ------------
__global__ void k_zero(unsigned* __restrict__ p, int count) {
    int i = blockIdx.x * 256 + threadIdx.x;
    if (i < count) p[i] = 0u;
}

// ---------------- degree histogram (out-deg for demb, in-deg for GCN norm) ----------
__global__ void k_hist(const int* __restrict__ ei, int E, int n,
                       unsigned* __restrict__ deg_out, unsigned* __restrict__ deg_in) {
    int e = blockIdx.x * 256 + threadIdx.x;
    if (e < E) {
        unsigned s = (unsigned)ei[e];
        unsigned d = (unsigned)ei[(size_t)E + e];
        if (s >= (unsigned)n) s = 0;   // armor: garbage -> finite wrong answer, not fault
        if (d >= (unsigned)n) d = 0;
        atomicAdd(&deg_out[s], 1u);
        atomicAdd(&deg_in[d], 1u);
    }
}

// ---------------- max out-degree ----------------------------------------------------
__global__ void k_max(const unsigned* __restrict__ deg, int n, unsigned* __restrict__ out) {
    __shared__ unsigned red[4];
    int i = blockIdx.x * 256 + threadIdx.x;
    unsigned v = (i < n) ? deg[i] : 0u;
    for (int o = 32; o; o >>= 1) v = max(v, (unsigned)__shfl_down((int)v, o));
    if ((threadIdx.x & 63) == 0) red[threadIdx.x >> 6] = v;
    __syncthreads();
    if (threadIdx.x == 0) {
        unsigned m = max(max(red[0], red[1]), max(red[2], red[3]));
        atomicMax(out, m);
    }
}

// ---------------- 3-kernel exclusive scan of deg_in -> CSR row_start ----------------
__global__ void k_scan1(const unsigned* __restrict__ deg, int n,
                        unsigned* __restrict__ rs, unsigned* __restrict__ bs) {
    __shared__ unsigned tmp[256];
    int i = blockIdx.x * 256 + threadIdx.x;
    unsigned v = (i < n) ? deg[i] : 0u;
    tmp[threadIdx.x] = v;
    __syncthreads();
    for (int o = 1; o < 256; o <<= 1) {
        unsigned t = (threadIdx.x >= (unsigned)o) ? tmp[threadIdx.x - o] : 0u;
        __syncthreads();
        tmp[threadIdx.x] += t;
        __syncthreads();
    }
    if (i < n) rs[i] = tmp[threadIdx.x] - v;
    if (threadIdx.x == 255) bs[blockIdx.x] = tmp[255];
}

__global__ void k_scan2(unsigned* __restrict__ bs, int nb) {  // nb <= 512
    __shared__ unsigned tmp[512];
    unsigned v = ((int)threadIdx.x < nb) ? bs[threadIdx.x] : 0u;
    tmp[threadIdx.x] = v;
    __syncthreads();
    for (int o = 1; o < 512; o <<= 1) {
        unsigned t = (threadIdx.x >= (unsigned)o) ? tmp[threadIdx.x - o] : 0u;
        __syncthreads();
        tmp[threadIdx.x] += t;
        __syncthreads();
    }
    if ((int)threadIdx.x < nb) bs[threadIdx.x] = tmp[threadIdx.x] - v;
}

__global__ void k_scan3(unsigned* __restrict__ rs, const unsigned* __restrict__ bs,
                        unsigned* __restrict__ cur, int n) {
    int i = blockIdx.x * 256 + threadIdx.x;
    if (i < n) {
        unsigned v = rs[i] + bs[blockIdx.x];
        rs[i] = v;
        cur[i] = v;
    }
}

// ---------------- scatter edges into CSR (sorted by dst) ----------------------------
__global__ void k_scatter(const int* __restrict__ ei, int E, int n,
                          unsigned* __restrict__ cur, unsigned* __restrict__ csr,
                          int csr_cap) {
    int e = blockIdx.x * 256 + threadIdx.x;
    if (e < E) {
        unsigned s = (unsigned)ei[e];
        unsigned d = (unsigned)ei[(size_t)E + e];
        if (s >= (unsigned)n) s = 0;
        if (d >= (unsigned)n) d = 0;
        unsigned pos = atomicAdd(&cur[d], 1u);
        if (pos < (unsigned)csr_cap) csr[pos] = s;
    }
}

// ---------------- per-node scalars (k_dot fused in-block) ---------------------------
__global__ void k_nodeprep(const unsigned* __restrict__ deg_out,
                           const unsigned* __restrict__ deg_in,
                           const float* __restrict__ param1, const float* __restrict__ param2,
                           const float* __restrict__ dW, const float* __restrict__ db,
                           const float* __restrict__ aW, const float* __restrict__ ab,
                           const unsigned* __restrict__ maxdeg, int n,
                           float* __restrict__ scale1, float* __restrict__ scale2,
                           float* __restrict__ ndarr, float* __restrict__ dinv) {
    __shared__ float sAB[2];
    int t = threadIdx.x;
    if (t < 64) {  // dw = sigmoid(nd*A + B): collapse deg_W@att_W to 2 scalars
        float a = dW[t] * aW[t];
        float b = db[t] * aW[t];
        for (int o = 32; o; o >>= 1) {
            a += __shfl_down(a, o);
            b += __shfl_down(b, o);
        }
        if (t == 0) { sAB[0] = a; sAB[1] = b + ab[0]; }
    }
    __syncthreads();
    int i = blockIdx.x * 256 + t;
    if (i >= n) return;
    float A = sAB[0], B = sAB[1];
    float maxf = (float)(*maxdeg);
    float nd = (float)deg_out[i] / maxf;
    float s = fmaf(nd, A, B);
    float dw = 1.f / (1.f + expf(-s));
    scale1[i] = param1[i] * dw;
    scale2[i] = param2[i] * dw;
    ndarr[i] = nd;
    dinv[i] = rsqrtf((float)(deg_in[i] + 1u));  // self-loop included
}

// ---------------- dense GEMM: Hout[n,NOUT] = A[n,K] @ W[K,NOUT] ---------------------
// 64 rows/block, 256 threads; thread owns 2 cols x RPG rows. A staged transposed in LDS.
// VIRT=true generates A = [x*s1 | (nd*deg_W+deg_b)*s1] on the fly (GEMM1).
template <int K, int NOUT, int CPT, bool VIRT>
__global__ __launch_bounds__(256) void k_gemm(
    const float* __restrict__ A, const float* __restrict__ Wg, float* __restrict__ Hout,
    int n, const float* __restrict__ x, const float* __restrict__ ndarr,
    const float* __restrict__ scale1, const float* __restrict__ dW,
    const float* __restrict__ db) {
    constexpr int RPG = CPT / 4;       // rows per thread
    constexpr int AST = 68;            // LDS row stride (16B aligned, bank-skewed)
    constexpr bool FULL2 = (2 * CPT <= NOUT);
    __shared__ float Alds[K * AST];
    const int tid = threadIdx.x;
    const int blockRow = blockIdx.x * 64;

    for (int idx = tid; idx < 64 * K; idx += 256) {
        int row = idx / K, k = idx - row * K;
        int grow = blockRow + row;
        float v = 0.f;
        if (grow < n) {
            if (VIRT) {
                float s1 = scale1[grow];
                v = (k < 128) ? x[(size_t)grow * 128 + k] * s1
                              : fmaf(ndarr[grow], dW[k - 128], db[k - 128]) * s1;
            } else {
                v = A[(size_t)grow * K + k];
            }
        }
        Alds[k * AST + row] = v;
    }
    __syncthreads();

    const int c = tid % CPT;
    const int rg = tid / CPT;
    const int rbase = rg * RPG;
    float acc0[RPG], acc1[RPG];
#pragma unroll
    for (int r = 0; r < RPG; r++) { acc0[r] = 0.f; acc1[r] = 0.f; }

    for (int k = 0; k < K; k++) {
        float w0 = Wg[k * NOUT + c];
        float w1 = (FULL2 || c + CPT < NOUT) ? Wg[k * NOUT + c + CPT] : 0.f;
        const float* ar = &Alds[k * AST + rbase];
#pragma unroll
        for (int r = 0; r < RPG; r += 4) {
            float4 av = *(const float4*)(ar + r);
            acc0[r + 0] = fmaf(av.x, w0, acc0[r + 0]); acc1[r + 0] = fmaf(av.x, w1, acc1[r + 0]);
            acc0[r + 1] = fmaf(av.y, w0, acc0[r + 1]); acc1[r + 1] = fmaf(av.y, w1, acc1[r + 1]);
            acc0[r + 2] = fmaf(av.z, w0, acc0[r + 2]); acc1[r + 2] = fmaf(av.z, w1, acc1[r + 2]);
            acc0[r + 3] = fmaf(av.w, w0, acc0[r + 3]); acc1[r + 3] = fmaf(av.w, w1, acc1[r + 3]);
        }
    }
#pragma unroll
    for (int r = 0; r < RPG; r++) {
        int grow = blockRow + rbase + r;
        if (grow < n) {
            Hout[(size_t)grow * NOUT + c] = acc0[r];
            if (FULL2 || c + CPT < NOUT) Hout[(size_t)grow * NOUT + (c + CPT)] = acc1[r];
        }
    }
}

// ---------------- sparse aggregation (CSR gather, no atomics) + fused epilogue ------
// out[i] = dinv[i] * (sum_{j in N(i)} dinv[j]*h[j] + dinv[i]*h[i])
// Unroll-4 edge loop: 4 independent row loads in flight per wave (MLP).
// EPI 1: relu(+b)*scale2 -> x1   EPI 2: relu(+b)+x1[:, :64] -> x2   EPI 3: +b, log_softmax
template <int D, int EPI, bool GUARD>
__global__ void k_agg(const float* __restrict__ Hm, const unsigned* __restrict__ row_start,
                      const unsigned* __restrict__ deg_in, const unsigned* __restrict__ csr,
                      const float* __restrict__ dinv, const float* __restrict__ bias,
                      const float* __restrict__ aux, float* __restrict__ Out, int n) {
    int node = blockIdx.x;
    if (node >= n) return;
    int c = threadIdx.x;
    unsigned beg = row_start[node];
    unsigned cnt = deg_in[node];
    float di = dinv[node];
    const bool act = !GUARD || (c < D);
    float acc = act ? di * Hm[(size_t)node * D + c] : 0.f;

    unsigned e = 0;
    for (; e + 4 <= cnt; e += 4) {
        unsigned s0 = csr[beg + e + 0];
        unsigned s1 = csr[beg + e + 1];
        unsigned s2 = csr[beg + e + 2];
        unsigned s3 = csr[beg + e + 3];
        float w0 = dinv[s0], w1 = dinv[s1], w2 = dinv[s2], w3 = dinv[s3];
        if (act) {
            float h0 = Hm[(size_t)s0 * D + c];
            float h1 = Hm[(size_t)s1 * D + c];
            float h2 = Hm[(size_t)s2 * D + c];
            float h3 = Hm[(size_t)s3 * D + c];
            acc = fmaf(w0, h0, acc);
            acc = fmaf(w1, h1, acc);
            acc = fmaf(w2, h2, acc);
            acc = fmaf(w3, h3, acc);
        }
    }
    for (; e < cnt; ++e) {
        unsigned s0 = csr[beg + e];
        float w0 = dinv[s0];
        if (act) acc = fmaf(w0, Hm[(size_t)s0 * D + c], acc);
    }
    acc *= di;

    if (EPI == 1) {
        float v = fmaxf(acc + bias[c], 0.f) * aux[node];
        Out[(size_t)node * D + c] = v;
    } else if (EPI == 2) {
        float v = fmaxf(acc + bias[c], 0.f) + aux[(size_t)node * 128 + c];
        Out[(size_t)node * D + c] = v;
    } else {
        float t = act ? (acc + bias[c]) : -INFINITY;
        float m = t;
        for (int o = 32; o; o >>= 1) m = fmaxf(m, __shfl_xor(m, o));
        float p = act ? expf(t - m) : 0.f;
        float ssum = p;
        for (int o = 32; o; o >>= 1) ssum += __shfl_xor(ssum, o);
        if (act) Out[(size_t)node * D + c] = t - m - logf(ssum);
    }
}

extern "C" void kernel_launch(void* const* d_in, const int* in_sizes, int n_in,
                              void* d_out, int out_size, void* d_ws, size_t ws_size,
                              hipStream_t stream) {
    const float* x = (const float*)d_in[0];
    const int* ei = (const int*)d_in[1];     // harness stages integers as int32
    const float* param1 = (const float*)d_in[2];
    const float* param2 = (const float*)d_in[3];
    const float* dW = (const float*)d_in[4];
    const float* db = (const float*)d_in[5];
    const float* aW = (const float*)d_in[6];
    const float* ab = (const float*)d_in[7];
    const float* W1 = (const float*)d_in[8];
    const float* b1 = (const float*)d_in[9];
    const float* W2 = (const float*)d_in[10];
    const float* b2 = (const float*)d_in[11];
    const float* W3 = (const float*)d_in[12];
    const float* b3 = (const float*)d_in[13];
    float* out = (float*)d_out;

    const int n = in_sizes[2];       // 100000 (param1 length)
    const int E = in_sizes[1] / 2;   // 1600000
    const int nb = (n + 255) / 256;  // 391 (must be <= 512 for k_scan2)

    char* p = (char*)d_ws;
    auto alloc = [&](size_t bytes) { char* r = p; p += WS_ALIGN(bytes); return r; };
    unsigned* deg_out = (unsigned*)alloc((size_t)n * 4);
    unsigned* deg_in = (unsigned*)alloc((size_t)n * 4);
    unsigned* maxdeg = (unsigned*)alloc(256);
    unsigned* row_start = (unsigned*)alloc((size_t)n * 4);
    unsigned* cursor = (unsigned*)alloc((size_t)n * 4);
    unsigned* bs = (unsigned*)alloc(4096);
    float* scale1 = (float*)alloc((size_t)n * 4);
    float* scale2 = (float*)alloc((size_t)n * 4);
    float* ndarr = (float*)alloc((size_t)n * 4);
    float* dinv = (float*)alloc((size_t)n * 4);
    unsigned* csr = (unsigned*)alloc((size_t)E * 4);
    float* h1 = (float*)alloc((size_t)n * 128 * 4);  // h1; later h2 (lo half) + x2 (hi half)
    float* x1 = (float*)alloc((size_t)n * 128 * 4);  // x1; later h3
    float* h2 = h1;
    float* x2 = h1 + (size_t)n * 64;
    float* h3 = x1;

    dim3 b256(256);
    // zero deg_out, deg_in, AND maxdeg — span computed from actual (aligned) pointers
    int zcount = (int)((((char*)maxdeg - (char*)deg_out) + 256) / 4);
    k_zero<<<dim3((zcount + 255) / 256), b256, 0, stream>>>(deg_out, zcount);

    k_hist<<<dim3((E + 255) / 256), b256, 0, stream>>>(ei, E, n, deg_out, deg_in);
    k_max<<<dim3(nb), b256, 0, stream>>>(deg_out, n, maxdeg);
    k_scan1<<<dim3(nb), b256, 0, stream>>>(deg_in, n, row_start, bs);
    k_scan2<<<dim3(1), dim3(512), 0, stream>>>(bs, nb);
    k_scan3<<<dim3(nb), b256, 0, stream>>>(row_start, bs, cursor, n);
    k_scatter<<<dim3((E + 255) / 256), b256, 0, stream>>>(ei, E, n, cursor, csr, E);
    k_nodeprep<<<dim3(nb), b256, 0, stream>>>(deg_out, deg_in, param1, param2, dW, db, aW, ab,
                                              maxdeg, n, scale1, scale2, ndarr, dinv);

    int gb = (n + 63) / 64;
    k_gemm<192, 128, 64, true><<<dim3(gb), b256, 0, stream>>>(nullptr, W1, h1, n, x, ndarr,
                                                              scale1, dW, db);
    k_agg<128, 1, false><<<dim3(n), dim3(128), 0, stream>>>(h1, row_start, deg_in, csr, dinv,
                                                            b1, scale2, x1, n);
    k_gemm<128, 64, 32, false><<<dim3(gb), b256, 0, stream>>>(x1, W2, h2, n, nullptr, nullptr,
                                                              nullptr, nullptr, nullptr);
    k_agg<64, 2, false><<<dim3(n), dim3(64), 0, stream>>>(h2, row_start, deg_in, csr, dinv,
                                                          b2, x1, x2, n);
    k_gemm<64, 40, 32, false><<<dim3(gb), b256, 0, stream>>>(x2, W3, h3, n, nullptr, nullptr,
                                                             nullptr, nullptr, nullptr);
    k_agg<40, 3, true><<<dim3(n), dim3(64), 0, stream>>>(h3, row_start, deg_in, csr, dinv,
                                                         b3, nullptr, out, n);
}

// Round 11
// 785.175 us; speedup vs baseline: 1.0983x; 1.0397x over previous
//
#include <hip/hip_runtime.h>
#include <hip/hip_bf16.h>
#include <math.h>

#define WS_ALIGN(x) (((x) + 255) & ~(size_t)255)

// ---------------- zero-fill (replaces hipMemsetAsync for capture safety) ------------
__global__ void k_zero(unsigned* __restrict__ p, int count) {
    int i = blockIdx.x * 256 + threadIdx.x;
    if (i < count) p[i] = 0u;
}

// ---------------- degree histogram (out-deg for demb, in-deg for GCN norm) ----------
__global__ void k_hist(const int* __restrict__ ei, int E, int n,
                       unsigned* __restrict__ deg_out, unsigned* __restrict__ deg_in) {
    int e = blockIdx.x * 256 + threadIdx.x;
    if (e < E) {
        unsigned s = (unsigned)ei[e];
        unsigned d = (unsigned)ei[(size_t)E + e];
        if (s >= (unsigned)n) s = 0;   // armor: garbage -> finite wrong answer, not fault
        if (d >= (unsigned)n) d = 0;
        atomicAdd(&deg_out[s], 1u);
        atomicAdd(&deg_in[d], 1u);
    }
}

// ---------------- max out-degree ----------------------------------------------------
__global__ void k_max(const unsigned* __restrict__ deg, int n, unsigned* __restrict__ out) {
    __shared__ unsigned red[4];
    int i = blockIdx.x * 256 + threadIdx.x;
    unsigned v = (i < n) ? deg[i] : 0u;
    for (int o = 32; o; o >>= 1) v = max(v, (unsigned)__shfl_down((int)v, o));
    if ((threadIdx.x & 63) == 0) red[threadIdx.x >> 6] = v;
    __syncthreads();
    if (threadIdx.x == 0) {
        unsigned m = max(max(red[0], red[1]), max(red[2], red[3]));
        atomicMax(out, m);
    }
}

// ---------------- 3-kernel exclusive scan of deg_in -> CSR row_start ----------------
__global__ void k_scan1(const unsigned* __restrict__ deg, int n,
                        unsigned* __restrict__ rs, unsigned* __restrict__ bs) {
    __shared__ unsigned tmp[256];
    int i = blockIdx.x * 256 + threadIdx.x;
    unsigned v = (i < n) ? deg[i] : 0u;
    tmp[threadIdx.x] = v;
    __syncthreads();
    for (int o = 1; o < 256; o <<= 1) {
        unsigned t = (threadIdx.x >= (unsigned)o) ? tmp[threadIdx.x - o] : 0u;
        __syncthreads();
        tmp[threadIdx.x] += t;
        __syncthreads();
    }
    if (i < n) rs[i] = tmp[threadIdx.x] - v;
    if (threadIdx.x == 255) bs[blockIdx.x] = tmp[255];
}

__global__ void k_scan2(unsigned* __restrict__ bs, int nb) {  // nb <= 512
    __shared__ unsigned tmp[512];
    unsigned v = ((int)threadIdx.x < nb) ? bs[threadIdx.x] : 0u;
    tmp[threadIdx.x] = v;
    __syncthreads();
    for (int o = 1; o < 512; o <<= 1) {
        unsigned t = (threadIdx.x >= (unsigned)o) ? tmp[threadIdx.x - o] : 0u;
        __syncthreads();
        tmp[threadIdx.x] += t;
        __syncthreads();
    }
    if ((int)threadIdx.x < nb) bs[threadIdx.x] = tmp[threadIdx.x] - v;
}

__global__ void k_scan3(unsigned* __restrict__ rs, const unsigned* __restrict__ bs,
                        unsigned* __restrict__ cur, int n) {
    int i = blockIdx.x * 256 + threadIdx.x;
    if (i < n) {
        unsigned v = rs[i] + bs[blockIdx.x];
        rs[i] = v;
        cur[i] = v;
    }
}

// ---------------- scatter edges into CSR (sorted by dst) ----------------------------
__global__ void k_scatter(const int* __restrict__ ei, int E, int n,
                          unsigned* __restrict__ cur, unsigned* __restrict__ csr,
                          int csr_cap) {
    int e = blockIdx.x * 256 + threadIdx.x;
    if (e < E) {
        unsigned s = (unsigned)ei[e];
        unsigned d = (unsigned)ei[(size_t)E + e];
        if (s >= (unsigned)n) s = 0;
        if (d >= (unsigned)n) d = 0;
        unsigned pos = atomicAdd(&cur[d], 1u);
        if (pos < (unsigned)csr_cap) csr[pos] = s;
    }
}

// ---------------- per-node scalars (k_dot fused in-block) ---------------------------
__global__ void k_nodeprep(const unsigned* __restrict__ deg_out,
                           const unsigned* __restrict__ deg_in,
                           const float* __restrict__ param1, const float* __restrict__ param2,
                           const float* __restrict__ dW, const float* __restrict__ db,
                           const float* __restrict__ aW, const float* __restrict__ ab,
                           const unsigned* __restrict__ maxdeg, int n,
                           float* __restrict__ scale1, float* __restrict__ scale2,
                           float* __restrict__ ndarr, float* __restrict__ dinv) {
    __shared__ float sAB[2];
    int t = threadIdx.x;
    if (t < 64) {  // dw = sigmoid(nd*A + B): collapse deg_W@att_W to 2 scalars
        float a = dW[t] * aW[t];
        float b = db[t] * aW[t];
        for (int o = 32; o; o >>= 1) {
            a += __shfl_down(a, o);
            b += __shfl_down(b, o);
        }
        if (t == 0) { sAB[0] = a; sAB[1] = b + ab[0]; }
    }
    __syncthreads();
    int i = blockIdx.x * 256 + t;
    if (i >= n) return;
    float A = sAB[0], B = sAB[1];
    float maxf = (float)(*maxdeg);
    float nd = (float)deg_out[i] / maxf;
    float s = fmaf(nd, A, B);
    float dw = 1.f / (1.f + expf(-s));
    scale1[i] = param1[i] * dw;
    scale2[i] = param2[i] * dw;
    ndarr[i] = nd;
    dinv[i] = rsqrtf((float)(deg_in[i] + 1u));  // self-loop included
}

// ---------------- P/Q precompute: collapse demb columns of GEMM1 to rank-2 ----------
// P[c] = sum_j dW[j]*W1[(128+j)*128+c], Q[c] = sum_j db[j]*W1[(128+j)*128+c]
__global__ void k_pq(const float* __restrict__ dW, const float* __restrict__ db,
                     const float* __restrict__ W1, float* __restrict__ PQ) {
    int c = threadIdx.x;  // 128 threads
    float p = 0.f, q = 0.f;
    for (int j = 0; j < 64; ++j) {
        float w = W1[(size_t)(128 + j) * 128 + c];
        p = fmaf(dW[j], w, p);
        q = fmaf(db[j], w, q);
    }
    PQ[c] = p;
    PQ[128 + c] = q;
}

// ---------------- dense GEMM: Hout[n,NOUT] = A[n,K] @ W[K,NOUT] ---------------------
// 64 rows/block, 256 threads; thread owns 2 cols x RPG rows. A staged transposed in LDS.
// EPIPQ=true (GEMM1): Hout = s1[row]*(acc + nd[row]*P[c] + Q[c])  (rank-2 demb term).
template <int K, int NOUT, int CPT, bool EPIPQ>
__global__ __launch_bounds__(256) void k_gemm(
    const float* __restrict__ A, const float* __restrict__ Wg, float* __restrict__ Hout,
    int n, const float* __restrict__ scale1, const float* __restrict__ ndarr,
    const float* __restrict__ PQ) {
    constexpr int RPG = CPT / 4;       // rows per thread
    constexpr int AST = 68;            // LDS row stride (16B aligned, bank-skewed)
    constexpr bool FULL2 = (2 * CPT <= NOUT);
    __shared__ float Alds[K * AST];
    const int tid = threadIdx.x;
    const int blockRow = blockIdx.x * 64;

    for (int idx = tid; idx < 64 * K; idx += 256) {
        int row = idx / K, k = idx - row * K;
        int grow = blockRow + row;
        float v = (grow < n) ? A[(size_t)grow * K + k] : 0.f;
        Alds[k * AST + row] = v;
    }
    __syncthreads();

    const int c = tid % CPT;
    const int rg = tid / CPT;
    const int rbase = rg * RPG;
    float acc0[RPG], acc1[RPG];
#pragma unroll
    for (int r = 0; r < RPG; r++) { acc0[r] = 0.f; acc1[r] = 0.f; }

    for (int k = 0; k < K; k++) {
        float w0 = Wg[k * NOUT + c];
        float w1 = (FULL2 || c + CPT < NOUT) ? Wg[k * NOUT + c + CPT] : 0.f;
        const float* ar = &Alds[k * AST + rbase];
#pragma unroll
        for (int r = 0; r < RPG; r += 4) {
            float4 av = *(const float4*)(ar + r);
            acc0[r + 0] = fmaf(av.x, w0, acc0[r + 0]); acc1[r + 0] = fmaf(av.x, w1, acc1[r + 0]);
            acc0[r + 1] = fmaf(av.y, w0, acc0[r + 1]); acc1[r + 1] = fmaf(av.y, w1, acc1[r + 1]);
            acc0[r + 2] = fmaf(av.z, w0, acc0[r + 2]); acc1[r + 2] = fmaf(av.z, w1, acc1[r + 2]);
            acc0[r + 3] = fmaf(av.w, w0, acc0[r + 3]); acc1[r + 3] = fmaf(av.w, w1, acc1[r + 3]);
        }
    }

    float pc0 = 0.f, qc0 = 0.f, pc1 = 0.f, qc1 = 0.f;
    if (EPIPQ) {
        pc0 = PQ[c]; qc0 = PQ[128 + c];
        pc1 = PQ[c + CPT]; qc1 = PQ[128 + c + CPT];
    }
#pragma unroll
    for (int r = 0; r < RPG; r++) {
        int grow = blockRow + rbase + r;
        if (grow < n) {
            if (EPIPQ) {
                float s1 = scale1[grow];
                float nd = ndarr[grow];
                Hout[(size_t)grow * NOUT + c] = s1 * (acc0[r] + fmaf(nd, pc0, qc0));
                Hout[(size_t)grow * NOUT + (c + CPT)] = s1 * (acc1[r] + fmaf(nd, pc1, qc1));
            } else {
                Hout[(size_t)grow * NOUT + c] = acc0[r];
                if (FULL2 || c + CPT < NOUT) Hout[(size_t)grow * NOUT + (c + CPT)] = acc1[r];
            }
        }
    }
}

// ---------------- sparse aggregation (CSR gather, no atomics) + fused epilogue ------
// out[i] = dinv[i] * (sum_{j in N(i)} dinv[j]*h[j] + dinv[i]*h[i])
// Unroll-4 edge loop: 4 independent row loads in flight per wave (MLP).
// EPI 1: relu(+b)*scale2 -> x1   EPI 2: relu(+b)+x1[:, :64] -> x2   EPI 3: +b, log_softmax
template <int D, int EPI, bool GUARD>
__global__ void k_agg(const float* __restrict__ Hm, const unsigned* __restrict__ row_start,
                      const unsigned* __restrict__ deg_in, const unsigned* __restrict__ csr,
                      const float* __restrict__ dinv, const float* __restrict__ bias,
                      const float* __restrict__ aux, float* __restrict__ Out, int n) {
    int node = blockIdx.x;
    if (node >= n) return;
    int c = threadIdx.x;
    unsigned beg = row_start[node];
    unsigned cnt = deg_in[node];
    float di = dinv[node];
    const bool act = !GUARD || (c < D);
    float acc = act ? di * Hm[(size_t)node * D + c] : 0.f;

    unsigned e = 0;
    for (; e + 4 <= cnt; e += 4) {
        unsigned s0 = csr[beg + e + 0];
        unsigned s1 = csr[beg + e + 1];
        unsigned s2 = csr[beg + e + 2];
        unsigned s3 = csr[beg + e + 3];
        float w0 = dinv[s0], w1 = dinv[s1], w2 = dinv[s2], w3 = dinv[s3];
        if (act) {
            float h0 = Hm[(size_t)s0 * D + c];
            float h1 = Hm[(size_t)s1 * D + c];
            float h2 = Hm[(size_t)s2 * D + c];
            float h3 = Hm[(size_t)s3 * D + c];
            acc = fmaf(w0, h0, acc);
            acc = fmaf(w1, h1, acc);
            acc = fmaf(w2, h2, acc);
            acc = fmaf(w3, h3, acc);
        }
    }
    for (; e < cnt; ++e) {
        unsigned s0 = csr[beg + e];
        float w0 = dinv[s0];
        if (act) acc = fmaf(w0, Hm[(size_t)s0 * D + c], acc);
    }
    acc *= di;

    if (EPI == 1) {
        float v = fmaxf(acc + bias[c], 0.f) * aux[node];
        Out[(size_t)node * D + c] = v;
    } else if (EPI == 2) {
        float v = fmaxf(acc + bias[c], 0.f) + aux[(size_t)node * 128 + c];
        Out[(size_t)node * D + c] = v;
    } else {
        float t = act ? (acc + bias[c]) : -INFINITY;
        float m = t;
        for (int o = 32; o; o >>= 1) m = fmaxf(m, __shfl_xor(m, o));
        float p = act ? expf(t - m) : 0.f;
        float ssum = p;
        for (int o = 32; o; o >>= 1) ssum += __shfl_xor(ssum, o);
        if (act) Out[(size_t)node * D + c] = t - m - logf(ssum);
    }
}

extern "C" void kernel_launch(void* const* d_in, const int* in_sizes, int n_in,
                              void* d_out, int out_size, void* d_ws, size_t ws_size,
                              hipStream_t stream) {
    const float* x = (const float*)d_in[0];
    const int* ei = (const int*)d_in[1];     // harness stages integers as int32
    const float* param1 = (const float*)d_in[2];
    const float* param2 = (const float*)d_in[3];
    const float* dW = (const float*)d_in[4];
    const float* db = (const float*)d_in[5];
    const float* aW = (const float*)d_in[6];
    const float* ab = (const float*)d_in[7];
    const float* W1 = (const float*)d_in[8];
    const float* b1 = (const float*)d_in[9];
    const float* W2 = (const float*)d_in[10];
    const float* b2 = (const float*)d_in[11];
    const float* W3 = (const float*)d_in[12];
    const float* b3 = (const float*)d_in[13];
    float* out = (float*)d_out;

    const int n = in_sizes[2];       // 100000 (param1 length)
    const int E = in_sizes[1] / 2;   // 1600000
    const int nb = (n + 255) / 256;  // 391 (must be <= 512 for k_scan2)

    char* p = (char*)d_ws;
    auto alloc = [&](size_t bytes) { char* r = p; p += WS_ALIGN(bytes); return r; };
    unsigned* deg_out = (unsigned*)alloc((size_t)n * 4);
    unsigned* deg_in = (unsigned*)alloc((size_t)n * 4);
    unsigned* maxdeg = (unsigned*)alloc(256);
    unsigned* row_start = (unsigned*)alloc((size_t)n * 4);
    unsigned* cursor = (unsigned*)alloc((size_t)n * 4);
    unsigned* bs = (unsigned*)alloc(4096);
    float* scale1 = (float*)alloc((size_t)n * 4);
    float* scale2 = (float*)alloc((size_t)n * 4);
    float* ndarr = (float*)alloc((size_t)n * 4);
    float* dinv = (float*)alloc((size_t)n * 4);
    float* PQ = (float*)alloc(1024);
    unsigned* csr = (unsigned*)alloc((size_t)E * 4);
    float* h1 = (float*)alloc((size_t)n * 128 * 4);  // h1; later h2 (lo half) + x2 (hi half)
    float* x1 = (float*)alloc((size_t)n * 128 * 4);  // x1; later h3
    float* h2 = h1;
    float* x2 = h1 + (size_t)n * 64;
    float* h3 = x1;

    dim3 b256(256);
    // zero deg_out, deg_in, AND maxdeg — span computed from actual (aligned) pointers
    int zcount = (int)((((char*)maxdeg - (char*)deg_out) + 256) / 4);
    k_zero<<<dim3((zcount + 255) / 256), b256, 0, stream>>>(deg_out, zcount);

    k_hist<<<dim3((E + 255) / 256), b256, 0, stream>>>(ei, E, n, deg_out, deg_in);
    k_max<<<dim3(nb), b256, 0, stream>>>(deg_out, n, maxdeg);
    k_scan1<<<dim3(nb), b256, 0, stream>>>(deg_in, n, row_start, bs);
    k_scan2<<<dim3(1), dim3(512), 0, stream>>>(bs, nb);
    k_scan3<<<dim3(nb), b256, 0, stream>>>(row_start, bs, cursor, n);
    k_scatter<<<dim3((E + 255) / 256), b256, 0, stream>>>(ei, E, n, cursor, csr, E);
    k_nodeprep<<<dim3(nb), b256, 0, stream>>>(deg_out, deg_in, param1, param2, dW, db, aW, ab,
                                              maxdeg, n, scale1, scale2, ndarr, dinv);
    k_pq<<<dim3(1), dim3(128), 0, stream>>>(dW, db, W1, PQ);

    int gb = (n + 63) / 64;
    k_gemm<128, 128, 64, true><<<dim3(gb), b256, 0, stream>>>(x, W1, h1, n, scale1, ndarr,
                                                              PQ);
    k_agg<128, 1, false><<<dim3(n), dim3(128), 0, stream>>>(h1, row_start, deg_in, csr, dinv,
                                                            b1, scale2, x1, n);
    k_gemm<128, 64, 32, false><<<dim3(gb), b256, 0, stream>>>(x1, W2, h2, n, nullptr, nullptr,
                                                              nullptr);
    k_agg<64, 2, false><<<dim3(n), dim3(64), 0, stream>>>(h2, row_start, deg_in, csr, dinv,
                                                          b2, x1, x2, n);
    k_gemm<64, 40, 32, false><<<dim3(gb), b256, 0, stream>>>(x2, W3, h3, n, nullptr, nullptr,
                                                             nullptr);
    k_agg<40, 3, true><<<dim3(n), dim3(64), 0, stream>>>(h3, row_start, deg_in, csr, dinv,
                                                         b3, nullptr, out, n);
}

// Round 12
// 753.455 us; speedup vs baseline: 1.1445x; 1.0421x over previous
//
#include <hip/hip_runtime.h>
#include <hip/hip_bf16.h>
#include <math.h>

#define WS_ALIGN(x) (((x) + 255) & ~(size_t)255)

// ---------------- zero-fill (replaces hipMemsetAsync for capture safety) ------------
__global__ void k_zero(unsigned* __restrict__ p, int count) {
    int i = blockIdx.x * 256 + threadIdx.x;
    if (i < count) p[i] = 0u;
}

// ---------------- degree histogram (out-deg for demb, in-deg for GCN norm) ----------
__global__ void k_hist(const int* __restrict__ ei, int E, int n,
                       unsigned* __restrict__ deg_out, unsigned* __restrict__ deg_in) {
    int e = blockIdx.x * 256 + threadIdx.x;
    if (e < E) {
        unsigned s = (unsigned)ei[e];
        unsigned d = (unsigned)ei[(size_t)E + e];
        if (s >= (unsigned)n) s = 0;   // armor: garbage -> finite wrong answer, not fault
        if (d >= (unsigned)n) d = 0;
        atomicAdd(&deg_out[s], 1u);
        atomicAdd(&deg_in[d], 1u);
    }
}

// ---------------- max out-degree ----------------------------------------------------
__global__ void k_max(const unsigned* __restrict__ deg, int n, unsigned* __restrict__ out) {
    __shared__ unsigned red[4];
    int i = blockIdx.x * 256 + threadIdx.x;
    unsigned v = (i < n) ? deg[i] : 0u;
    for (int o = 32; o; o >>= 1) v = max(v, (unsigned)__shfl_down((int)v, o));
    if ((threadIdx.x & 63) == 0) red[threadIdx.x >> 6] = v;
    __syncthreads();
    if (threadIdx.x == 0) {
        unsigned m = max(max(red[0], red[1]), max(red[2], red[3]));
        atomicMax(out, m);
    }
}

// ---------------- 3-kernel exclusive scan of deg_in -> CSR row_start ----------------
__global__ void k_scan1(const unsigned* __restrict__ deg, int n,
                        unsigned* __restrict__ rs, unsigned* __restrict__ bs) {
    __shared__ unsigned tmp[256];
    int i = blockIdx.x * 256 + threadIdx.x;
    unsigned v = (i < n) ? deg[i] : 0u;
    tmp[threadIdx.x] = v;
    __syncthreads();
    for (int o = 1; o < 256; o <<= 1) {
        unsigned t = (threadIdx.x >= (unsigned)o) ? tmp[threadIdx.x - o] : 0u;
        __syncthreads();
        tmp[threadIdx.x] += t;
        __syncthreads();
    }
    if (i < n) rs[i] = tmp[threadIdx.x] - v;
    if (threadIdx.x == 255) bs[blockIdx.x] = tmp[255];
}

__global__ void k_scan2(unsigned* __restrict__ bs, int nb) {  // nb <= 512
    __shared__ unsigned tmp[512];
    unsigned v = ((int)threadIdx.x < nb) ? bs[threadIdx.x] : 0u;
    tmp[threadIdx.x] = v;
    __syncthreads();
    for (int o = 1; o < 512; o <<= 1) {
        unsigned t = (threadIdx.x >= (unsigned)o) ? tmp[threadIdx.x - o] : 0u;
        __syncthreads();
        tmp[threadIdx.x] += t;
        __syncthreads();
    }
    if ((int)threadIdx.x < nb) bs[threadIdx.x] = tmp[threadIdx.x] - v;
}

__global__ void k_scan3(unsigned* __restrict__ rs, const unsigned* __restrict__ bs,
                        unsigned* __restrict__ cur, int n) {
    int i = blockIdx.x * 256 + threadIdx.x;
    if (i < n) {
        unsigned v = rs[i] + bs[blockIdx.x];
        rs[i] = v;
        cur[i] = v;
    }
}

// ---------------- scatter edges into CSR (sorted by dst) ----------------------------
__global__ void k_scatter(const int* __restrict__ ei, int E, int n,
                          unsigned* __restrict__ cur, unsigned* __restrict__ csr,
                          int csr_cap) {
    int e = blockIdx.x * 256 + threadIdx.x;
    if (e < E) {
        unsigned s = (unsigned)ei[e];
        unsigned d = (unsigned)ei[(size_t)E + e];
        if (s >= (unsigned)n) s = 0;
        if (d >= (unsigned)n) d = 0;
        unsigned pos = atomicAdd(&cur[d], 1u);
        if (pos < (unsigned)csr_cap) csr[pos] = s;
    }
}

// ---------------- per-node scalars (k_dot fused in-block) ---------------------------
// scale1 = param1*dw*dinv  (dinv folded: GEMM1 epilogue produces h1' = dinv ⊙ h1)
__global__ void k_nodeprep(const unsigned* __restrict__ deg_out,
                           const unsigned* __restrict__ deg_in,
                           const float* __restrict__ param1, const float* __restrict__ param2,
                           const float* __restrict__ dW, const float* __restrict__ db,
                           const float* __restrict__ aW, const float* __restrict__ ab,
                           const unsigned* __restrict__ maxdeg, int n,
                           float* __restrict__ scale1, float* __restrict__ scale2,
                           float* __restrict__ ndarr, float* __restrict__ dinv) {
    __shared__ float sAB[2];
    int t = threadIdx.x;
    if (t < 64) {  // dw = sigmoid(nd*A + B): collapse deg_W@att_W to 2 scalars
        float a = dW[t] * aW[t];
        float b = db[t] * aW[t];
        for (int o = 32; o; o >>= 1) {
            a += __shfl_down(a, o);
            b += __shfl_down(b, o);
        }
        if (t == 0) { sAB[0] = a; sAB[1] = b + ab[0]; }
    }
    __syncthreads();
    int i = blockIdx.x * 256 + t;
    if (i >= n) return;
    float A = sAB[0], B = sAB[1];
    float maxf = (float)(*maxdeg);
    float nd = (float)deg_out[i] / maxf;
    float s = fmaf(nd, A, B);
    float dw = 1.f / (1.f + expf(-s));
    float di = rsqrtf((float)(deg_in[i] + 1u));  // self-loop included
    scale1[i] = param1[i] * dw * di;
    scale2[i] = param2[i] * dw;
    ndarr[i] = nd;
    dinv[i] = di;
}

// ---------------- P/Q precompute: collapse demb columns of GEMM1 to rank-2 ----------
// P[c] = sum_j dW[j]*W1[(128+j)*128+c], Q[c] = sum_j db[j]*W1[(128+j)*128+c]
__global__ void k_pq(const float* __restrict__ dW, const float* __restrict__ db,
                     const float* __restrict__ W1, float* __restrict__ PQ) {
    int c = threadIdx.x;  // 128 threads
    float p = 0.f, q = 0.f;
    for (int j = 0; j < 64; ++j) {
        float w = W1[(size_t)(128 + j) * 128 + c];
        p = fmaf(dW[j], w, p);
        q = fmaf(db[j], w, q);
    }
    PQ[c] = p;
    PQ[128 + c] = q;
}

// ---------------- dense GEMM: Hout[n,NOUT] = rowscale ⊙ (A[n,K] @ W[K,NOUT]) --------
// 64 rows/block, 256 threads; thread owns 2 cols x RPG rows. A staged transposed in LDS.
// EPIPQ (GEMM1): Hout = rs[row]*(acc + nd[row]*P[c] + Q[c]); rs = param1*dw*dinv.
// SCALED (GEMM2/3): Hout = rs[row]*acc; rs = dinv.
template <int K, int NOUT, int CPT, bool EPIPQ, bool SCALED>
__global__ __launch_bounds__(256) void k_gemm(
    const float* __restrict__ A, const float* __restrict__ Wg, float* __restrict__ Hout,
    int n, const float* __restrict__ rowscale, const float* __restrict__ ndarr,
    const float* __restrict__ PQ) {
    constexpr int RPG = CPT / 4;       // rows per thread
    constexpr int AST = 68;            // LDS row stride (16B aligned, bank-skewed)
    constexpr bool FULL2 = (2 * CPT <= NOUT);
    __shared__ float Alds[K * AST];
    const int tid = threadIdx.x;
    const int blockRow = blockIdx.x * 64;

    for (int idx = tid; idx < 64 * K; idx += 256) {
        int row = idx / K, k = idx - row * K;
        int grow = blockRow + row;
        float v = (grow < n) ? A[(size_t)grow * K + k] : 0.f;
        Alds[k * AST + row] = v;
    }
    __syncthreads();

    const int c = tid % CPT;
    const int rg = tid / CPT;
    const int rbase = rg * RPG;
    float acc0[RPG], acc1[RPG];
#pragma unroll
    for (int r = 0; r < RPG; r++) { acc0[r] = 0.f; acc1[r] = 0.f; }

    for (int k = 0; k < K; k++) {
        float w0 = Wg[k * NOUT + c];
        float w1 = (FULL2 || c + CPT < NOUT) ? Wg[k * NOUT + c + CPT] : 0.f;
        const float* ar = &Alds[k * AST + rbase];
#pragma unroll
        for (int r = 0; r < RPG; r += 4) {
            float4 av = *(const float4*)(ar + r);
            acc0[r + 0] = fmaf(av.x, w0, acc0[r + 0]); acc1[r + 0] = fmaf(av.x, w1, acc1[r + 0]);
            acc0[r + 1] = fmaf(av.y, w0, acc0[r + 1]); acc1[r + 1] = fmaf(av.y, w1, acc1[r + 1]);
            acc0[r + 2] = fmaf(av.z, w0, acc0[r + 2]); acc1[r + 2] = fmaf(av.z, w1, acc1[r + 2]);
            acc0[r + 3] = fmaf(av.w, w0, acc0[r + 3]); acc1[r + 3] = fmaf(av.w, w1, acc1[r + 3]);
        }
    }

    float pc0 = 0.f, qc0 = 0.f, pc1 = 0.f, qc1 = 0.f;
    if (EPIPQ) {
        pc0 = PQ[c]; qc0 = PQ[128 + c];
        pc1 = PQ[c + CPT]; qc1 = PQ[128 + c + CPT];
    }
#pragma unroll
    for (int r = 0; r < RPG; r++) {
        int grow = blockRow + rbase + r;
        if (grow < n) {
            if (EPIPQ) {
                float s1 = rowscale[grow];
                float nd = ndarr[grow];
                Hout[(size_t)grow * NOUT + c] = s1 * (acc0[r] + fmaf(nd, pc0, qc0));
                Hout[(size_t)grow * NOUT + (c + CPT)] = s1 * (acc1[r] + fmaf(nd, pc1, qc1));
            } else if (SCALED) {
                float s1 = rowscale[grow];
                Hout[(size_t)grow * NOUT + c] = s1 * acc0[r];
                if (FULL2 || c + CPT < NOUT)
                    Hout[(size_t)grow * NOUT + (c + CPT)] = s1 * acc1[r];
            } else {
                Hout[(size_t)grow * NOUT + c] = acc0[r];
                if (FULL2 || c + CPT < NOUT) Hout[(size_t)grow * NOUT + (c + CPT)] = acc1[r];
            }
        }
    }
}

// ---------------- sparse aggregation (CSR gather, no atomics) + fused epilogue ------
// Hm rows are pre-scaled by dinv[src]; out[i] = dinv[i]*(Hm[i] + sum_{j in N(i)} Hm[j])
// Unroll-8 main + 4 mid + scalar tail: up to 8 independent row loads in flight (MLP).
// EPI 1: relu(+b)*scale2 -> x1   EPI 2: relu(+b)+x1[:, :64] -> x2   EPI 3: +b, log_softmax
template <int D, int EPI, bool GUARD>
__global__ void k_agg(const float* __restrict__ Hm, const unsigned* __restrict__ row_start,
                      const unsigned* __restrict__ deg_in, const unsigned* __restrict__ csr,
                      const float* __restrict__ dinv, const float* __restrict__ bias,
                      const float* __restrict__ aux, float* __restrict__ Out, int n) {
    int node = blockIdx.x;
    if (node >= n) return;
    int c = threadIdx.x;
    unsigned beg = row_start[node];
    unsigned cnt = deg_in[node];
    float di = dinv[node];
    const bool act = !GUARD || (c < D);
    float acc = act ? Hm[(size_t)node * D + c] : 0.f;  // self (dinv-folded)

    unsigned e = 0;
    for (; e + 8 <= cnt; e += 8) {
        unsigned s0 = csr[beg + e + 0], s1 = csr[beg + e + 1];
        unsigned s2 = csr[beg + e + 2], s3 = csr[beg + e + 3];
        unsigned s4 = csr[beg + e + 4], s5 = csr[beg + e + 5];
        unsigned s6 = csr[beg + e + 6], s7 = csr[beg + e + 7];
        if (act) {
            float h0 = Hm[(size_t)s0 * D + c], h1 = Hm[(size_t)s1 * D + c];
            float h2 = Hm[(size_t)s2 * D + c], h3 = Hm[(size_t)s3 * D + c];
            float h4 = Hm[(size_t)s4 * D + c], h5 = Hm[(size_t)s5 * D + c];
            float h6 = Hm[(size_t)s6 * D + c], h7 = Hm[(size_t)s7 * D + c];
            acc += h0 + h1 + h2 + h3 + h4 + h5 + h6 + h7;
        }
    }
    for (; e + 4 <= cnt; e += 4) {
        unsigned s0 = csr[beg + e + 0], s1 = csr[beg + e + 1];
        unsigned s2 = csr[beg + e + 2], s3 = csr[beg + e + 3];
        if (act) {
            float h0 = Hm[(size_t)s0 * D + c], h1 = Hm[(size_t)s1 * D + c];
            float h2 = Hm[(size_t)s2 * D + c], h3 = Hm[(size_t)s3 * D + c];
            acc += h0 + h1 + h2 + h3;
        }
    }
    for (; e < cnt; ++e) {
        unsigned s0 = csr[beg + e];
        if (act) acc += Hm[(size_t)s0 * D + c];
    }
    acc *= di;

    if (EPI == 1) {
        float v = fmaxf(acc + bias[c], 0.f) * aux[node];
        Out[(size_t)node * D + c] = v;
    } else if (EPI == 2) {
        float v = fmaxf(acc + bias[c], 0.f) + aux[(size_t)node * 128 + c];
        Out[(size_t)node * D + c] = v;
    } else {
        float t = act ? (acc + bias[c]) : -INFINITY;
        float m = t;
        for (int o = 32; o; o >>= 1) m = fmaxf(m, __shfl_xor(m, o));
        float p = act ? expf(t - m) : 0.f;
        float ssum = p;
        for (int o = 32; o; o >>= 1) ssum += __shfl_xor(ssum, o);
        if (act) Out[(size_t)node * D + c] = t - m - logf(ssum);
    }
}

extern "C" void kernel_launch(void* const* d_in, const int* in_sizes, int n_in,
                              void* d_out, int out_size, void* d_ws, size_t ws_size,
                              hipStream_t stream) {
    const float* x = (const float*)d_in[0];
    const int* ei = (const int*)d_in[1];     // harness stages integers as int32
    const float* param1 = (const float*)d_in[2];
    const float* param2 = (const float*)d_in[3];
    const float* dW = (const float*)d_in[4];
    const float* db = (const float*)d_in[5];
    const float* aW = (const float*)d_in[6];
    const float* ab = (const float*)d_in[7];
    const float* W1 = (const float*)d_in[8];
    const float* b1 = (const float*)d_in[9];
    const float* W2 = (const float*)d_in[10];
    const float* b2 = (const float*)d_in[11];
    const float* W3 = (const float*)d_in[12];
    const float* b3 = (const float*)d_in[13];
    float* out = (float*)d_out;

    const int n = in_sizes[2];       // 100000 (param1 length)
    const int E = in_sizes[1] / 2;   // 1600000
    const int nb = (n + 255) / 256;  // 391 (must be <= 512 for k_scan2)

    char* p = (char*)d_ws;
    auto alloc = [&](size_t bytes) { char* r = p; p += WS_ALIGN(bytes); return r; };
    unsigned* deg_out = (unsigned*)alloc((size_t)n * 4);
    unsigned* deg_in = (unsigned*)alloc((size_t)n * 4);
    unsigned* maxdeg = (unsigned*)alloc(256);
    unsigned* row_start = (unsigned*)alloc((size_t)n * 4);
    unsigned* cursor = (unsigned*)alloc((size_t)n * 4);
    unsigned* bs = (unsigned*)alloc(4096);
    float* scale1 = (float*)alloc((size_t)n * 4);
    float* scale2 = (float*)alloc((size_t)n * 4);
    float* ndarr = (float*)alloc((size_t)n * 4);
    float* dinv = (float*)alloc((size_t)n * 4);
    float* PQ = (float*)alloc(1024);
    unsigned* csr = (unsigned*)alloc((size_t)E * 4);
    float* h1 = (float*)alloc((size_t)n * 128 * 4);  // h1; later h2 (lo half) + x2 (hi half)
    float* x1 = (float*)alloc((size_t)n * 128 * 4);  // x1; later h3
    float* h2 = h1;
    float* x2 = h1 + (size_t)n * 64;
    float* h3 = x1;

    dim3 b256(256);
    // zero deg_out, deg_in, AND maxdeg — span computed from actual (aligned) pointers
    int zcount = (int)((((char*)maxdeg - (char*)deg_out) + 256) / 4);
    k_zero<<<dim3((zcount + 255) / 256), b256, 0, stream>>>(deg_out, zcount);

    k_hist<<<dim3((E + 255) / 256), b256, 0, stream>>>(ei, E, n, deg_out, deg_in);
    k_max<<<dim3(nb), b256, 0, stream>>>(deg_out, n, maxdeg);
    k_scan1<<<dim3(nb), b256, 0, stream>>>(deg_in, n, row_start, bs);
    k_scan2<<<dim3(1), dim3(512), 0, stream>>>(bs, nb);
    k_scan3<<<dim3(nb), b256, 0, stream>>>(row_start, bs, cursor, n);
    k_scatter<<<dim3((E + 255) / 256), b256, 0, stream>>>(ei, E, n, cursor, csr, E);
    k_nodeprep<<<dim3(nb), b256, 0, stream>>>(deg_out, deg_in, param1, param2, dW, db, aW, ab,
                                              maxdeg, n, scale1, scale2, ndarr, dinv);
    k_pq<<<dim3(1), dim3(128), 0, stream>>>(dW, db, W1, PQ);

    int gb = (n + 63) / 64;
    k_gemm<128, 128, 64, true, true><<<dim3(gb), b256, 0, stream>>>(x, W1, h1, n, scale1,
                                                                    ndarr, PQ);
    k_agg<128, 1, false><<<dim3(n), dim3(128), 0, stream>>>(h1, row_start, deg_in, csr, dinv,
                                                            b1, scale2, x1, n);
    k_gemm<128, 64, 32, false, true><<<dim3(gb), b256, 0, stream>>>(x1, W2, h2, n, dinv,
                                                                    nullptr, nullptr);
    k_agg<64, 2, false><<<dim3(n), dim3(64), 0, stream>>>(h2, row_start, deg_in, csr, dinv,
                                                          b2, x1, x2, n);
    k_gemm<64, 40, 32, false, true><<<dim3(gb), b256, 0, stream>>>(x2, W3, h3, n, dinv,
                                                                   nullptr, nullptr);
    k_agg<40, 3, true><<<dim3(n), dim3(64), 0, stream>>>(h3, row_start, deg_in, csr, dinv,
                                                         b3, nullptr, out, n);
}

// Round 13
// 747.468 us; speedup vs baseline: 1.1537x; 1.0080x over previous
//
#include <hip/hip_runtime.h>
#include <hip/hip_bf16.h>
#include <math.h>

#define WS_ALIGN(x) (((x) + 255) & ~(size_t)255)

// ---------------- zero-fill (replaces hipMemsetAsync for capture safety) ------------
__global__ void k_zero(unsigned* __restrict__ p, int count) {
    int i = blockIdx.x * 256 + threadIdx.x;
    if (i < count) p[i] = 0u;
}

// ---------------- sharded degree histogram (8 shards by blockIdx&7) -----------------
__global__ void k_hist8(const int* __restrict__ ei, int E, int n,
                        unsigned* __restrict__ do8, unsigned* __restrict__ di8) {
    int e = blockIdx.x * 256 + threadIdx.x;
    size_t sh = (size_t)(blockIdx.x & 7) * n;
    if (e < E) {
        unsigned s = (unsigned)ei[e];
        unsigned d = (unsigned)ei[(size_t)E + e];
        if (s >= (unsigned)n) s = 0;   // armor: garbage -> finite wrong answer, not fault
        if (d >= (unsigned)n) d = 0;
        atomicAdd(&do8[sh + s], 1u);
        atomicAdd(&di8[sh + d], 1u);
    }
}

// ---------------- reduce shards -> deg_out/deg_in, fused max(deg_out) ---------------
__global__ void k_reduce8(const unsigned* __restrict__ do8, const unsigned* __restrict__ di8,
                          int n, unsigned* __restrict__ deg_out,
                          unsigned* __restrict__ deg_in, unsigned* __restrict__ maxdeg) {
    __shared__ unsigned red[4];
    int i = blockIdx.x * 256 + threadIdx.x;
    unsigned so = 0, si = 0;
    if (i < n) {
#pragma unroll
        for (int k = 0; k < 8; k++) {
            so += do8[(size_t)k * n + i];
            si += di8[(size_t)k * n + i];
        }
        deg_out[i] = so;
        deg_in[i] = si;
    }
    unsigned v = (i < n) ? so : 0u;
    for (int o = 32; o; o >>= 1) v = max(v, (unsigned)__shfl_down((int)v, o));
    if ((threadIdx.x & 63) == 0) red[threadIdx.x >> 6] = v;
    __syncthreads();
    if (threadIdx.x == 0) {
        unsigned m = max(max(red[0], red[1]), max(red[2], red[3]));
        atomicMax(maxdeg, m);
    }
}

// ---------------- 3-kernel exclusive scan of deg_in -> CSR row_start ----------------
__global__ void k_scan1(const unsigned* __restrict__ deg, int n,
                        unsigned* __restrict__ rs, unsigned* __restrict__ bs) {
    __shared__ unsigned tmp[256];
    int i = blockIdx.x * 256 + threadIdx.x;
    unsigned v = (i < n) ? deg[i] : 0u;
    tmp[threadIdx.x] = v;
    __syncthreads();
    for (int o = 1; o < 256; o <<= 1) {
        unsigned t = (threadIdx.x >= (unsigned)o) ? tmp[threadIdx.x - o] : 0u;
        __syncthreads();
        tmp[threadIdx.x] += t;
        __syncthreads();
    }
    if (i < n) rs[i] = tmp[threadIdx.x] - v;
    if (threadIdx.x == 255) bs[blockIdx.x] = tmp[255];
}

__global__ void k_scan2(unsigned* __restrict__ bs, int nb) {  // nb <= 512
    __shared__ unsigned tmp[512];
    unsigned v = ((int)threadIdx.x < nb) ? bs[threadIdx.x] : 0u;
    tmp[threadIdx.x] = v;
    __syncthreads();
    for (int o = 1; o < 512; o <<= 1) {
        unsigned t = (threadIdx.x >= (unsigned)o) ? tmp[threadIdx.x - o] : 0u;
        __syncthreads();
        tmp[threadIdx.x] += t;
        __syncthreads();
    }
    if ((int)threadIdx.x < nb) bs[threadIdx.x] = tmp[threadIdx.x] - v;
}

__global__ void k_scan3(unsigned* __restrict__ rs, const unsigned* __restrict__ bs,
                        unsigned* __restrict__ cur, int n) {
    int i = blockIdx.x * 256 + threadIdx.x;
    if (i < n) {
        unsigned v = rs[i] + bs[blockIdx.x];
        rs[i] = v;
        cur[i] = v;
    }
}

// ---------------- scatter edges into CSR (sorted by dst) ----------------------------
__global__ void k_scatter(const int* __restrict__ ei, int E, int n,
                          unsigned* __restrict__ cur, unsigned* __restrict__ csr,
                          int csr_cap) {
    int e = blockIdx.x * 256 + threadIdx.x;
    if (e < E) {
        unsigned s = (unsigned)ei[e];
        unsigned d = (unsigned)ei[(size_t)E + e];
        if (s >= (unsigned)n) s = 0;
        if (d >= (unsigned)n) d = 0;
        unsigned pos = atomicAdd(&cur[d], 1u);
        if (pos < (unsigned)csr_cap) csr[pos] = s;
    }
}

// ---------------- per-node scalars (k_dot fused in-block) ---------------------------
// scale1 = param1*dw*dinv  (dinv folded: GEMM1 epilogue produces h1' = dinv ⊙ h1)
__global__ void k_nodeprep(const unsigned* __restrict__ deg_out,
                           const unsigned* __restrict__ deg_in,
                           const float* __restrict__ param1, const float* __restrict__ param2,
                           const float* __restrict__ dW, const float* __restrict__ db,
                           const float* __restrict__ aW, const float* __restrict__ ab,
                           const unsigned* __restrict__ maxdeg, int n,
                           float* __restrict__ scale1, float* __restrict__ scale2,
                           float* __restrict__ ndarr, float* __restrict__ dinv) {
    __shared__ float sAB[2];
    int t = threadIdx.x;
    if (t < 64) {  // dw = sigmoid(nd*A + B): collapse deg_W@att_W to 2 scalars
        float a = dW[t] * aW[t];
        float b = db[t] * aW[t];
        for (int o = 32; o; o >>= 1) {
            a += __shfl_down(a, o);
            b += __shfl_down(b, o);
        }
        if (t == 0) { sAB[0] = a; sAB[1] = b + ab[0]; }
    }
    __syncthreads();
    int i = blockIdx.x * 256 + t;
    if (i >= n) return;
    float A = sAB[0], B = sAB[1];
    float maxf = (float)(*maxdeg);
    float nd = (float)deg_out[i] / maxf;
    float s = fmaf(nd, A, B);
    float dw = 1.f / (1.f + expf(-s));
    float di = rsqrtf((float)(deg_in[i] + 1u));  // self-loop included
    scale1[i] = param1[i] * dw * di;
    scale2[i] = param2[i] * dw;
    ndarr[i] = nd;
    dinv[i] = di;
}

// ---------------- P/Q precompute: collapse demb columns of GEMM1 to rank-2 ----------
// P[c] = sum_j dW[j]*W1[(128+j)*128+c], Q[c] = sum_j db[j]*W1[(128+j)*128+c]
__global__ void k_pq(const float* __restrict__ dW, const float* __restrict__ db,
                     const float* __restrict__ W1, float* __restrict__ PQ) {
    int c = threadIdx.x;  // 128 threads
    float p = 0.f, q = 0.f;
    for (int j = 0; j < 64; ++j) {
        float w = W1[(size_t)(128 + j) * 128 + c];
        p = fmaf(dW[j], w, p);
        q = fmaf(db[j], w, q);
    }
    PQ[c] = p;
    PQ[128 + c] = q;
}

// ---------------- dense GEMM: Hout[n,NOUT] = rowscale ⊙ (A[n,K] @ W[K,NOUT]) --------
// 64 rows/block, 256 threads; thread owns 2 cols x RPG rows. A staged transposed in LDS.
// EPIPQ (GEMM1): Hout = rs[row]*(acc + nd[row]*P[c] + Q[c]); rs = param1*dw*dinv.
// SCALED (GEMM2/3): Hout = rs[row]*acc; rs = dinv.
template <int K, int NOUT, int CPT, bool EPIPQ, bool SCALED>
__global__ __launch_bounds__(256) void k_gemm(
    const float* __restrict__ A, const float* __restrict__ Wg, float* __restrict__ Hout,
    int n, const float* __restrict__ rowscale, const float* __restrict__ ndarr,
    const float* __restrict__ PQ) {
    constexpr int RPG = CPT / 4;       // rows per thread
    constexpr int AST = 68;            // LDS row stride (16B aligned, bank-skewed)
    constexpr bool FULL2 = (2 * CPT <= NOUT);
    __shared__ float Alds[K * AST];
    const int tid = threadIdx.x;
    const int blockRow = blockIdx.x * 64;

    for (int idx = tid; idx < 64 * K; idx += 256) {
        int row = idx / K, k = idx - row * K;
        int grow = blockRow + row;
        float v = (grow < n) ? A[(size_t)grow * K + k] : 0.f;
        Alds[k * AST + row] = v;
    }
    __syncthreads();

    const int c = tid % CPT;
    const int rg = tid / CPT;
    const int rbase = rg * RPG;
    float acc0[RPG], acc1[RPG];
#pragma unroll
    for (int r = 0; r < RPG; r++) { acc0[r] = 0.f; acc1[r] = 0.f; }

    for (int k = 0; k < K; k++) {
        float w0 = Wg[k * NOUT + c];
        float w1 = (FULL2 || c + CPT < NOUT) ? Wg[k * NOUT + c + CPT] : 0.f;
        const float* ar = &Alds[k * AST + rbase];
#pragma unroll
        for (int r = 0; r < RPG; r += 4) {
            float4 av = *(const float4*)(ar + r);
            acc0[r + 0] = fmaf(av.x, w0, acc0[r + 0]); acc1[r + 0] = fmaf(av.x, w1, acc1[r + 0]);
            acc0[r + 1] = fmaf(av.y, w0, acc0[r + 1]); acc1[r + 1] = fmaf(av.y, w1, acc1[r + 1]);
            acc0[r + 2] = fmaf(av.z, w0, acc0[r + 2]); acc1[r + 2] = fmaf(av.z, w1, acc1[r + 2]);
            acc0[r + 3] = fmaf(av.w, w0, acc0[r + 3]); acc1[r + 3] = fmaf(av.w, w1, acc1[r + 3]);
        }
    }

    float pc0 = 0.f, qc0 = 0.f, pc1 = 0.f, qc1 = 0.f;
    if (EPIPQ) {
        pc0 = PQ[c]; qc0 = PQ[128 + c];
        pc1 = PQ[c + CPT]; qc1 = PQ[128 + c + CPT];
    }
#pragma unroll
    for (int r = 0; r < RPG; r++) {
        int grow = blockRow + rbase + r;
        if (grow < n) {
            if (EPIPQ) {
                float s1 = rowscale[grow];
                float nd = ndarr[grow];
                Hout[(size_t)grow * NOUT + c] = s1 * (acc0[r] + fmaf(nd, pc0, qc0));
                Hout[(size_t)grow * NOUT + (c + CPT)] = s1 * (acc1[r] + fmaf(nd, pc1, qc1));
            } else if (SCALED) {
                float s1 = rowscale[grow];
                Hout[(size_t)grow * NOUT + c] = s1 * acc0[r];
                if (FULL2 || c + CPT < NOUT)
                    Hout[(size_t)grow * NOUT + (c + CPT)] = s1 * acc1[r];
            } else {
                Hout[(size_t)grow * NOUT + c] = acc0[r];
                if (FULL2 || c + CPT < NOUT) Hout[(size_t)grow * NOUT + (c + CPT)] = acc1[r];
            }
        }
    }
}

// ---------------- sparse aggregation (CSR gather, no atomics) + fused epilogue ------
// Hm rows are pre-scaled by dinv[src]; out[i] = dinv[i]*(Hm[i] + sum_{j in N(i)} Hm[j])
// Unroll-8 main + 4 mid + scalar tail: up to 8 independent row loads in flight (MLP).
// EPI 1: relu(+b)*scale2 -> x1   EPI 2: relu(+b)+x1[:, :64] -> x2   EPI 3: +b, log_softmax
template <int D, int EPI, bool GUARD>
__global__ void k_agg(const float* __restrict__ Hm, const unsigned* __restrict__ row_start,
                      const unsigned* __restrict__ deg_in, const unsigned* __restrict__ csr,
                      const float* __restrict__ dinv, const float* __restrict__ bias,
                      const float* __restrict__ aux, float* __restrict__ Out, int n) {
    int node = blockIdx.x;
    if (node >= n) return;
    int c = threadIdx.x;
    unsigned beg = row_start[node];
    unsigned cnt = deg_in[node];
    float di = dinv[node];
    const bool act = !GUARD || (c < D);
    float acc = act ? Hm[(size_t)node * D + c] : 0.f;  // self (dinv-folded)

    unsigned e = 0;
    for (; e + 8 <= cnt; e += 8) {
        unsigned s0 = csr[beg + e + 0], s1 = csr[beg + e + 1];
        unsigned s2 = csr[beg + e + 2], s3 = csr[beg + e + 3];
        unsigned s4 = csr[beg + e + 4], s5 = csr[beg + e + 5];
        unsigned s6 = csr[beg + e + 6], s7 = csr[beg + e + 7];
        if (act) {
            float h0 = Hm[(size_t)s0 * D + c], h1 = Hm[(size_t)s1 * D + c];
            float h2 = Hm[(size_t)s2 * D + c], h3 = Hm[(size_t)s3 * D + c];
            float h4 = Hm[(size_t)s4 * D + c], h5 = Hm[(size_t)s5 * D + c];
            float h6 = Hm[(size_t)s6 * D + c], h7 = Hm[(size_t)s7 * D + c];
            acc += h0 + h1 + h2 + h3 + h4 + h5 + h6 + h7;
        }
    }
    for (; e + 4 <= cnt; e += 4) {
        unsigned s0 = csr[beg + e + 0], s1 = csr[beg + e + 1];
        unsigned s2 = csr[beg + e + 2], s3 = csr[beg + e + 3];
        if (act) {
            float h0 = Hm[(size_t)s0 * D + c], h1 = Hm[(size_t)s1 * D + c];
            float h2 = Hm[(size_t)s2 * D + c], h3 = Hm[(size_t)s3 * D + c];
            acc += h0 + h1 + h2 + h3;
        }
    }
    for (; e < cnt; ++e) {
        unsigned s0 = csr[beg + e];
        if (act) acc += Hm[(size_t)s0 * D + c];
    }
    acc *= di;

    if (EPI == 1) {
        float v = fmaxf(acc + bias[c], 0.f) * aux[node];
        Out[(size_t)node * D + c] = v;
    } else if (EPI == 2) {
        float v = fmaxf(acc + bias[c], 0.f) + aux[(size_t)node * 128 + c];
        Out[(size_t)node * D + c] = v;
    } else {
        float t = act ? (acc + bias[c]) : -INFINITY;
        float m = t;
        for (int o = 32; o; o >>= 1) m = fmaxf(m, __shfl_xor(m, o));
        float p = act ? expf(t - m) : 0.f;
        float ssum = p;
        for (int o = 32; o; o >>= 1) ssum += __shfl_xor(ssum, o);
        if (act) Out[(size_t)node * D + c] = t - m - logf(ssum);
    }
}

extern "C" void kernel_launch(void* const* d_in, const int* in_sizes, int n_in,
                              void* d_out, int out_size, void* d_ws, size_t ws_size,
                              hipStream_t stream) {
    const float* x = (const float*)d_in[0];
    const int* ei = (const int*)d_in[1];     // harness stages integers as int32
    const float* param1 = (const float*)d_in[2];
    const float* param2 = (const float*)d_in[3];
    const float* dW = (const float*)d_in[4];
    const float* db = (const float*)d_in[5];
    const float* aW = (const float*)d_in[6];
    const float* ab = (const float*)d_in[7];
    const float* W1 = (const float*)d_in[8];
    const float* b1 = (const float*)d_in[9];
    const float* W2 = (const float*)d_in[10];
    const float* b2 = (const float*)d_in[11];
    const float* W3 = (const float*)d_in[12];
    const float* b3 = (const float*)d_in[13];
    float* out = (float*)d_out;

    const int n = in_sizes[2];       // 100000 (param1 length)
    const int E = in_sizes[1] / 2;   // 1600000
    const int nb = (n + 255) / 256;  // 391 (must be <= 512 for k_scan2)

    char* p = (char*)d_ws;
    auto alloc = [&](size_t bytes) { char* r = p; p += WS_ALIGN(bytes); return r; };
    unsigned* deg_out = (unsigned*)alloc((size_t)n * 4);
    unsigned* deg_in = (unsigned*)alloc((size_t)n * 4);
    unsigned* maxdeg = (unsigned*)alloc(256);
    unsigned* row_start = (unsigned*)alloc((size_t)n * 4);
    unsigned* cursor = (unsigned*)alloc((size_t)n * 4);
    unsigned* bs = (unsigned*)alloc(4096);
    float* scale1 = (float*)alloc((size_t)n * 4);
    float* scale2 = (float*)alloc((size_t)n * 4);
    float* ndarr = (float*)alloc((size_t)n * 4);
    float* dinv = (float*)alloc((size_t)n * 4);
    float* PQ = (float*)alloc(1024);
    unsigned* csr = (unsigned*)alloc((size_t)E * 4);
    float* h1 = (float*)alloc((size_t)n * 128 * 4);  // h1; later h2 (lo half) + x2 (hi half)
    float* x1 = (float*)alloc((size_t)n * 128 * 4);  // x1; later h3
    float* h2 = h1;
    float* x2 = h1 + (size_t)n * 64;
    float* h3 = x1;
    // sharded histograms alias h1 (dead before GEMM1 writes h1): 16n words = 6.4 MB
    unsigned* do8 = (unsigned*)h1;
    unsigned* di8 = do8 + (size_t)8 * n;

    dim3 b256(256);
    k_zero<<<dim3(1), b256, 0, stream>>>(maxdeg, 64);
    int shn = 16 * n;
    k_zero<<<dim3((shn + 255) / 256), b256, 0, stream>>>(do8, shn);

    k_hist8<<<dim3((E + 255) / 256), b256, 0, stream>>>(ei, E, n, do8, di8);
    k_reduce8<<<dim3(nb), b256, 0, stream>>>(do8, di8, n, deg_out, deg_in, maxdeg);
    k_scan1<<<dim3(nb), b256, 0, stream>>>(deg_in, n, row_start, bs);
    k_scan2<<<dim3(1), dim3(512), 0, stream>>>(bs, nb);
    k_scan3<<<dim3(nb), b256, 0, stream>>>(row_start, bs, cursor, n);
    k_scatter<<<dim3((E + 255) / 256), b256, 0, stream>>>(ei, E, n, cursor, csr, E);
    k_nodeprep<<<dim3(nb), b256, 0, stream>>>(deg_out, deg_in, param1, param2, dW, db, aW, ab,
                                              maxdeg, n, scale1, scale2, ndarr, dinv);
    k_pq<<<dim3(1), dim3(128), 0, stream>>>(dW, db, W1, PQ);

    int gb = (n + 63) / 64;
    k_gemm<128, 128, 64, true, true><<<dim3(gb), b256, 0, stream>>>(x, W1, h1, n, scale1,
                                                                    ndarr, PQ);
    k_agg<128, 1, false><<<dim3(n), dim3(128), 0, stream>>>(h1, row_start, deg_in, csr, dinv,
                                                            b1, scale2, x1, n);
    k_gemm<128, 64, 32, false, true><<<dim3(gb), b256, 0, stream>>>(x1, W2, h2, n, dinv,
                                                                    nullptr, nullptr);
    k_agg<64, 2, false><<<dim3(n), dim3(64), 0, stream>>>(h2, row_start, deg_in, csr, dinv,
                                                          b2, x1, x2, n);
    k_gemm<64, 40, 32, false, true><<<dim3(gb), b256, 0, stream>>>(x2, W3, h3, n, dinv,
                                                                   nullptr, nullptr);
    k_agg<40, 3, true><<<dim3(n), dim3(64), 0, stream>>>(h3, row_start, deg_in, csr, dinv,
                                                         b3, nullptr, out, n);
}